// Round 1
// baseline (1012.533 us; speedup 1.0000x reference)
//
#include <hip/hip_runtime.h>
#include <math.h>

#define KK 10
#define NN 96
#define TT 40
#define HID 48
#define NBIN 36

#define HZf 10.0f
#define R0f 0.5f
#define R1f 4.0f
#define RSTEPf ((4.0f - 0.5f) / 6.0f)
#define TWO_PIf 6.2831853071795864769f
#define TSTEPf (6.2831853071795864769f / 6.0f)

__device__ __forceinline__ float sigmoidf_(float x) { return 1.0f / (1.0f + expf(-x)); }

// ---------- conv1: (4,160,160) -> relu -> (16,80,80), stride 2, pad 2 ----------
__global__ void conv1_k(const float* __restrict__ img, const float* __restrict__ w,
                        const float* __restrict__ b, float* __restrict__ out) {
    int idx = blockIdx.x * blockDim.x + threadIdx.x;
    if (idx >= 16 * 80 * 80) return;
    int x = idx % 80, y = (idx / 80) % 80, o = idx / 6400;
    float acc = b[o];
    for (int c = 0; c < 4; c++) {
        for (int ky = 0; ky < 5; ky++) {
            int iy = y * 2 + ky - 2;
            if (iy < 0 || iy >= 160) continue;
            for (int kx = 0; kx < 5; kx++) {
                int ix = x * 2 + kx - 2;
                if (ix < 0 || ix >= 160) continue;
                acc += img[(c * 160 + iy) * 160 + ix] * w[((o * 4 + c) * 5 + ky) * 5 + kx];
            }
        }
    }
    out[idx] = fmaxf(acc, 0.0f);
}

// ---------- conv2: (16,80,80) -> relu -> (32,80,80), stride 1, pad 2 ----------
__global__ void conv2_k(const float* __restrict__ in, const float* __restrict__ w,
                        const float* __restrict__ b, float* __restrict__ out) {
    int idx = blockIdx.x * blockDim.x + threadIdx.x;
    if (idx >= 32 * 80 * 80) return;
    int x = idx % 80, y = (idx / 80) % 80, o = idx / 6400;
    float acc = b[o];
    for (int c = 0; c < 16; c++) {
        for (int ky = 0; ky < 5; ky++) {
            int iy = y + ky - 2;
            if (iy < 0 || iy >= 80) continue;
            for (int kx = 0; kx < 5; kx++) {
                int ix = x + kx - 2;
                if (ix < 0 || ix >= 80) continue;
                acc += in[(c * 80 + iy) * 80 + ix] * w[((o * 16 + c) * 5 + ky) * 5 + kx];
            }
        }
    }
    out[idx] = fmaxf(acc, 0.0f);
}

// ---------- weight transposes ----------
// wt_scf[b][d][o] = scf[o*1728 + b*48 + d]   (36*48*48)
// wih_lt[d][g] = wih[g*96 + d], wih_rt[d][g] = wih[g*96+48+d], whh_t[d][g] = whh[g*48+d]
__global__ void prep_w(const float* __restrict__ scf, const float* __restrict__ wih,
                       const float* __restrict__ whh, float* __restrict__ wt_scf,
                       float* __restrict__ wih_lt, float* __restrict__ wih_rt,
                       float* __restrict__ whh_t) {
    int idx = blockIdx.x * blockDim.x + threadIdx.x;
    if (idx < 36 * 48 * 48) {
        int o = idx % 48, d = (idx / 48) % 48, b = idx / 2304;
        wt_scf[idx] = scf[o * 1728 + b * 48 + d];
    }
    int idx2 = idx - 36 * 48 * 48;
    if (idx2 >= 0 && idx2 < 48 * 144) {
        int g = idx2 % 144, d = idx2 / 144;
        wih_lt[idx2] = wih[g * 96 + d];
        wih_rt[idx2] = wih[g * 96 + 48 + d];
        whh_t[idx2] = whh[g * 48 + d];
    }
}

// ---------- lhalf[t][row][48] = [feat(32) | relu(vel@fcvel)(16)] ----------
__global__ void lhalf_k(const float* __restrict__ yp, const float* __restrict__ cur,
                        const float* __restrict__ fmap, const float* __restrict__ vw,
                        const float* __restrict__ vb, float* __restrict__ lhalf) {
    int item = blockIdx.x;  // t*K*N + k*N + n
    int n = item % NN, k = (item / NN) % KK, t = item / (KK * NN);
    int lane = threadIdx.x;
    float lx = yp[((k * TT + t) * NN + n) * 2 + 0];
    float ly = yp[((k * TT + t) * NN + n) * 2 + 1];
    float px, py;
    if (t == 0) { px = cur[n * 2]; py = cur[n * 2 + 1]; }
    else { px = yp[((k * TT + t - 1) * NN + n) * 2]; py = yp[((k * TT + t - 1) * NN + n) * 2 + 1]; }
    float vx = (lx - px) * HZf, vy = (ly - py) * HZf;
    int ui = 40 - (int)ly;  // trunc toward zero, matches astype(int32)
    int vi = 40 - (int)lx;
    ui = min(max(ui, 0), 79);
    vi = min(max(vi, 0), 79);
    int row = k * NN + n;
    float* dst = lhalf + ((size_t)t * KK * NN + row) * 48;
    if (lane < 32) {
        dst[lane] = fmap[(lane * 80 + ui) * 80 + vi];
    } else if (lane < 48) {
        int f = lane - 32;
        float a = vb[f] + vx * vw[f * 2 + 0] + vy * vw[f * 2 + 1];
        dst[lane] = fmaxf(a, 0.0f);
    }
}

// ---------- bins: per (t,k,i) winner/count for 36 bins ----------
__global__ void bins_k(const float* __restrict__ yp, signed char* __restrict__ win,
                       unsigned char* __restrict__ cnt) {
    int item = blockIdx.x;  // (t*K + k)*96 + i
    int i = item % 96, k = (item / 96) % KK, t = item / (96 * KK);
    int tid = threadIdx.x;
    __shared__ int bin_s[96];
    __shared__ int val_s[96];
    float lix = yp[((k * TT + t) * NN + i) * 2], liy = yp[((k * TT + t) * NN + i) * 2 + 1];
    if (tid < 96) {
        int j = tid;
        float dx = yp[((k * TT + t) * NN + j) * 2] - lix;
        float dy = yp[((k * TT + t) * NN + j) * 2 + 1] - liy;
        float dist = sqrtf(dx * dx + dy * dy);
        bool valid = (dist >= R0f) && (dist <= R1f) && (j != i);
        float dsafe = fmaxf(dist, 1e-10f);
        float cost = fminf(fmaxf(dx / dsafe, -1.0f), 1.0f);
        float ac = acosf(cost);
        float theta = (dy < 0.0f) ? (TWO_PIf - ac) : ac;
        int ub = (int)((dist - R0f) / RSTEPf); ub = min(max(ub, 0), 5);
        int vb = (int)(theta / TSTEPf);        vb = min(max(vb, 0), 5);
        bin_s[j] = ub * 6 + vb;
        val_s[j] = valid ? 1 : 0;
    }
    __syncthreads();
    if (tid < NBIN) {
        int b = tid, c = 0, w = -1;
        for (int j = 0; j < 96; j++) {
            if (val_s[j] && bin_s[j] == b) { c++; w = j; }
        }
        win[(size_t)item * 36 + b] = (signed char)w;
        cnt[(size_t)item * 36 + b] = (unsigned char)c;
    }
}

// ---------- init h0 ----------
__global__ void init_h(const float* __restrict__ hx, float* __restrict__ hbuf) {
    int idx = blockIdx.x * blockDim.x + threadIdx.x;
    if (idx >= 960 * 48) return;
    int d = idx % 48, row = idx / 48, n = row % 96;
    hbuf[idx] = hx[n * 48 + d];
}

// ---------- one GRU step: 960 blocks x 64 lanes (one wave per row) ----------
__global__ __launch_bounds__(64) void step_k(
    int t, const float* __restrict__ hprev, float* __restrict__ hnext,
    const float* __restrict__ lhalf, const signed char* __restrict__ win,
    const unsigned char* __restrict__ cnt, const float* __restrict__ wt_scf,
    const float* __restrict__ wih_lt, const float* __restrict__ wih_rt,
    const float* __restrict__ whh_t, const float* __restrict__ bih,
    const float* __restrict__ bhh, const float* __restrict__ scfb,
    const float* __restrict__ score_w, float* __restrict__ score_acc) {
    int row = blockIdx.x, lane = threadIdx.x;
    __shared__ float sh_h[48], sh_rh[48], sh_gi[144], sh_gh[144];
    if (lane < 48) sh_h[lane] = hprev[row * 48 + lane];
    const signed char* wrow = win + ((size_t)t * 960 + row) * 36;
    const unsigned char* crow = cnt + ((size_t)t * 960 + row) * 36;
    // rhalf: sum over occupied bins of scale * W_b @ hidden[winner]
    float acc = (lane < 48) ? scfb[lane] : 0.0f;
    for (int b = 0; b < 36; b++) {
        int w = wrow[b];
        if (w < 0) continue;
        float sc = 1.0f / (float)crow[b];
        const float* hv = hprev + w * 48;  // hidden = h[:96]
        const float* wb = wt_scf + b * 2304;
        float part = 0.0f;
        if (lane < 48) {
#pragma unroll 8
            for (int d = 0; d < 48; d++) part += hv[d] * wb[d * 48 + lane];
        }
        acc += sc * part;
    }
    if (lane < 48) sh_rh[lane] = fmaxf(acc, 0.0f);
    __syncthreads();
    const float* lh = lhalf + ((size_t)t * 960 + row) * 48;
    for (int rep = 0; rep < 3; rep++) {
        if (lane < 48) {
            int g = rep * 48 + lane;
            float gi = bih[g], gh = bhh[g];
#pragma unroll 8
            for (int d = 0; d < 48; d++) {
                gi += lh[d] * wih_lt[d * 144 + g] + sh_rh[d] * wih_rt[d * 144 + g];
                gh += sh_h[d] * whh_t[d * 144 + g];
            }
            sh_gi[g] = gi;
            sh_gh[g] = gh;
        }
    }
    __syncthreads();
    float sv = 0.0f;
    if (lane < 48) {
        float r = sigmoidf_(sh_gi[lane] + sh_gh[lane]);
        float z = sigmoidf_(sh_gi[48 + lane] + sh_gh[48 + lane]);
        float ng = tanhf(sh_gi[96 + lane] + r * sh_gh[96 + lane]);
        float hn = (1.0f - z) * ng + z * sh_h[lane];
        hnext[row * 48 + lane] = hn;
        sv = hn * score_w[lane];
    }
    for (int off = 32; off; off >>= 1) sv += __shfl_down(sv, off);
    if (lane == 0) {
        float prev = (t == 0) ? 0.0f : score_acc[row];
        score_acc[row] = prev + sv;
    }
}

// ---------- epilogue: delta_y + score ----------
__global__ void final_k(const float* __restrict__ hlast, const float* __restrict__ score_acc,
                        const float* __restrict__ dyw, const float* __restrict__ dyb,
                        const float* __restrict__ scoreb, float* __restrict__ out) {
    int row = blockIdx.x, lane = threadIdx.x;
    int n = row % 96, k = row / 96;
    __shared__ float sh_h[48];
    if (lane < 48) sh_h[lane] = hlast[row * 48 + lane];
    __syncthreads();
    if (lane < 80) {
        float a = dyb[lane];
#pragma unroll 8
        for (int d = 0; d < 48; d++) a += sh_h[d] * dyw[lane * 48 + d];
        a = fmaxf(a, 0.0f);
        int j = lane / 40, tt = lane % 40;
        out[((k * TT + tt) * NN + n) * 2 + j] = a;
    } else if (lane == 80) {
        out[76800 + row] = score_acc[row] + 40.0f * scoreb[0];
    }
}

extern "C" void kernel_launch(void* const* d_in, const int* in_sizes, int n_in,
                              void* d_out, int out_size, void* d_ws, size_t ws_size,
                              hipStream_t stream) {
    const float* hx  = (const float*)d_in[0];
    const float* cur = (const float*)d_in[1];
    const float* yp  = (const float*)d_in[2];
    const float* img = (const float*)d_in[3];
    const float* c1w = (const float*)d_in[4];
    const float* c1b = (const float*)d_in[5];
    const float* c2w = (const float*)d_in[6];
    const float* c2b = (const float*)d_in[7];
    const float* vw  = (const float*)d_in[8];
    const float* vb  = (const float*)d_in[9];
    const float* wih = (const float*)d_in[10];
    const float* whh = (const float*)d_in[11];
    const float* bih = (const float*)d_in[12];
    const float* bhh = (const float*)d_in[13];
    const float* scfw = (const float*)d_in[14];
    const float* scfb = (const float*)d_in[15];
    const float* scw  = (const float*)d_in[16];
    const float* scb  = (const float*)d_in[17];
    const float* dyw  = (const float*)d_in[18];
    const float* dyb  = (const float*)d_in[19];
    float* out = (float*)d_out;

    char* ws = (char*)d_ws;
    float* fmap1 = (float*)(ws + 0);              // 409600 B
    float* fmap  = (float*)(ws + 409600);         // 819200 B
    float* lhalf = (float*)(ws + 1228800);        // 7372800 B
    signed char* win = (signed char*)(ws + 8601600);    // 1382400 B
    unsigned char* cnt = (unsigned char*)(ws + 9984000);// 1382400 B
    float* hbuf = (float*)(ws + 11366400);        // 2 * 184320 B
    float* score_acc = (float*)(ws + 11735040);   // 3840 B
    float* wt_scf = (float*)(ws + 11738880);      // 331776 B
    float* wih_lt = (float*)(ws + 12070656);      // 27648 B
    float* wih_rt = (float*)(ws + 12098304);      // 27648 B
    float* whh_t  = (float*)(ws + 12125952);      // 27648 B

    conv1_k<<<400, 256, 0, stream>>>(img, c1w, c1b, fmap1);
    conv2_k<<<800, 256, 0, stream>>>(fmap1, c2w, c2b, fmap);
    prep_w<<<(36 * 48 * 48 + 48 * 144 + 255) / 256, 256, 0, stream>>>(scfw, wih, whh, wt_scf,
                                                                      wih_lt, wih_rt, whh_t);
    lhalf_k<<<TT * KK * NN, 64, 0, stream>>>(yp, cur, fmap, vw, vb, lhalf);
    bins_k<<<TT * KK * 96, 128, 0, stream>>>(yp, win, cnt);
    init_h<<<(960 * 48 + 255) / 256, 256, 0, stream>>>(hx, hbuf);

    for (int t = 0; t < 40; t++) {
        const float* hp = hbuf + (t & 1) * 46080;
        float* hn = hbuf + ((t + 1) & 1) * 46080;
        step_k<<<960, 64, 0, stream>>>(t, hp, hn, lhalf, win, cnt, wt_scf, wih_lt, wih_rt,
                                       whh_t, bih, bhh, scfb, scw, score_acc);
    }
    final_k<<<960, 128, 0, stream>>>(hbuf /* (40&1)==0 */, score_acc, dyw, dyb, scb, out);
}